// Round 1
// baseline (295.416 us; speedup 1.0000x reference)
//
#include <hip/hip_runtime.h>
#include <hip/hip_bf16.h>
#include <math.h>

// Problem constants
constexpr int Bc = 2, Lc = 1024, Dc = 768, Hc = 12, dh = 64, Rc = 128;
constexpr int BL = Bc * Lc;          // 2048 tokens
constexpr int TD = 3 * Dc;           // 2304
constexpr int CH = 64;               // chunk length
constexpr int NC = Lc / CH;          // 16 chunks per sequence
constexpr int BH = Bc * Hc;          // 24

// ---------------- LayerNorm over D=768 ----------------
__global__ __launch_bounds__(256)
void ln_kernel(const float* __restrict__ x, const float* __restrict__ w,
               const float* __restrict__ bcoef, float* __restrict__ y) {
    int row = blockIdx.x;
    const float* xr = x + (size_t)row * Dc;
    float* yr = y + (size_t)row * Dc;
    int tid = threadIdx.x;
    float v[3];
    float s = 0.f;
#pragma unroll
    for (int i = 0; i < 3; i++) { v[i] = xr[tid + i * 256]; s += v[i]; }
    __shared__ float red[256];
    red[tid] = s; __syncthreads();
    for (int off = 128; off > 0; off >>= 1) {
        if (tid < off) red[tid] += red[tid + off];
        __syncthreads();
    }
    float mu = red[0] / (float)Dc;
    __syncthreads();
    float s2 = 0.f;
#pragma unroll
    for (int i = 0; i < 3; i++) { float d = v[i] - mu; s2 += d * d; }
    red[tid] = s2; __syncthreads();
    for (int off = 128; off > 0; off >>= 1) {
        if (tid < off) red[tid] += red[tid + off];
        __syncthreads();
    }
    float rstd = rsqrtf(red[0] / (float)Dc + 1e-5f);
#pragma unroll
    for (int i = 0; i < 3; i++) {
        int c = tid + i * 256;
        yr[c] = (v[i] - mu) * rstd * w[c] + bcoef[c];
    }
}

// ---------------- Tiled fp32 GEMM: C[M,N] = act(A[M,K] @ W[K,N] + bias) ----------------
// BM=BN=64, BK=16, 256 threads, 4x4 per thread. ACT: 0 none, 1 silu.
template <int ACT>
__global__ __launch_bounds__(256)
void gemm_kernel(const float* __restrict__ A, const float* __restrict__ W,
                 const float* __restrict__ bias, float* __restrict__ C,
                 int M, int N, int K) {
    __shared__ float As[16 * 68];   // [k][m], padded for b128 + conflict-free
    __shared__ float Bs[16 * 64];   // [k][n]
    int tid = threadIdx.x;
    int m0 = blockIdx.y * 64, n0 = blockIdx.x * 64;
    int tm = tid >> 4, tn = tid & 15;
    float acc[4][4] = {};
    for (int k0 = 0; k0 < K; k0 += 16) {
#pragma unroll
        for (int i = 0; i < 4; i++) {
            int e = tid + i * 256;
            int r = e >> 4, c = e & 15;
            As[c * 68 + r] = A[(size_t)(m0 + r) * K + k0 + c];
        }
#pragma unroll
        for (int i = 0; i < 4; i++) {
            int e = tid + i * 256;
            int r = e >> 6, c = e & 63;
            Bs[r * 64 + c] = W[(size_t)(k0 + r) * N + n0 + c];
        }
        __syncthreads();
#pragma unroll
        for (int k = 0; k < 16; k++) {
            float4 a4 = *reinterpret_cast<const float4*>(&As[k * 68 + tm * 4]);
            float4 b4 = *reinterpret_cast<const float4*>(&Bs[k * 64 + tn * 4]);
            float a[4] = {a4.x, a4.y, a4.z, a4.w};
            float b[4] = {b4.x, b4.y, b4.z, b4.w};
#pragma unroll
            for (int i = 0; i < 4; i++)
#pragma unroll
                for (int j = 0; j < 4; j++)
                    acc[i][j] = fmaf(a[i], b[j], acc[i][j]);
        }
        __syncthreads();
    }
#pragma unroll
    for (int i = 0; i < 4; i++) {
        int row = m0 + tm * 4 + i;
#pragma unroll
        for (int j = 0; j < 4; j++) {
            int col = n0 + tn * 4 + j;
            float v = acc[i][j];
            if (bias) v += bias[col];
            if (ACT == 1) v = v / (1.f + expf(-v));
            C[(size_t)row * N + col] = v;
        }
    }
}

// ---------------- Gate params: params = t @ Wb2 (128x60), then gate math ----------------
__global__ __launch_bounds__(256)
void gate_kernel(const float* __restrict__ tbuf, const float* __restrict__ Wb2,
                 const float* __restrict__ temperature,
                 float* __restrict__ gate_out, float* __restrict__ og) {
    int id = blockIdx.x * 256 + threadIdx.x;   // < 24576
    int tok = id / Hc, h = id % Hc;
    const float* tr = tbuf + (size_t)tok * Rc;
    float p[5] = {};
    for (int r = 0; r < Rc; r++) {
        float tv = tr[r];
        const float* wr = Wb2 + r * (Hc * 5) + h * 5;
#pragma unroll
        for (int c = 0; c < 5; c++) p[c] = fmaf(tv, wr[c], p[c]);
    }
    const float PI = 3.14159265358979323846f;
    float sem_amp = 1.f / (1.f + expf(-p[0]));
    float sem_phase = tanhf(p[1]) * PI;
    float ctx_amp = 1.f / (1.f + expf(-p[2]));
    float ctx_phase = tanhf(p[3]) * PI;
    float temp = fminf(fmaxf(temperature[0], 0.1f), 2.0f);
    float inter = tanhf(sem_amp * ctx_amp * cosf(sem_phase - ctx_phase)) * temp;
    float g = 1.f / (1.f + expf(-inter));
    gate_out[id] = g;
    og[id] = 1.f + g;
}

// ---------------- Phase A: per-chunk U_c = K^T diag(1+g) V, zc = sum K ----------------
__global__ __launch_bounds__(256)
void phaseA_kernel(const float* __restrict__ qkv, const float* __restrict__ og,
                   float* __restrict__ SU, float* __restrict__ zc) {
    int bid = blockIdx.x;           // bh*16 + c
    int bh = bid >> 4, c = bid & 15;
    int b = bh / Hc, h = bh % Hc;
    int tok0 = b * Lc + c * CH;
    __shared__ float Ks[64 * 64];   // k_f
    __shared__ float Vs[64 * 64];   // v * (1+g)
    int tid = threadIdx.x;
#pragma unroll
    for (int i = 0; i < 16; i++) {
        int e2 = tid + i * 256;
        int tt = e2 >> 6, dd = e2 & 63;
        size_t rowoff = (size_t)(tok0 + tt) * TD + h * dh;
        float kv = qkv[rowoff + Dc + dd];
        float vv = qkv[rowoff + 2 * Dc + dd];
        float gv = og[(size_t)(tok0 + tt) * Hc + h];
        Ks[tt * 64 + dd] = kv > 0.f ? kv + 1.f : expf(kv);
        Vs[tt * 64 + dd] = vv * gv;
    }
    __syncthreads();
    int e = tid & 63, d0 = (tid >> 6) * 16;
    float u[16] = {};
    for (int tt = 0; tt < 64; tt++) {
        float vv = Vs[tt * 64 + e];
#pragma unroll
        for (int j = 0; j < 16; j++)
            u[j] = fmaf(Ks[tt * 64 + d0 + j], vv, u[j]);
    }
    float* Uo = SU + (size_t)bid * 4096;
#pragma unroll
    for (int j = 0; j < 16; j++)
        Uo[(d0 + j) * 64 + e] = u[j];
    if (tid < 64) {
        float zsum = 0.f;
        for (int tt = 0; tt < 64; tt++) zsum += Ks[tt * 64 + tid];
        zc[bid * 64 + tid] = zsum;
    }
}

// ---------------- Phase B: exclusive prefix over chunks (in place) ----------------
__global__ __launch_bounds__(256)
void prefix_kernel(float* __restrict__ SU, float* __restrict__ zc) {
    int bh = blockIdx.x;
    int tid = threadIdx.x;
    float* S = SU + (size_t)bh * NC * 4096;
    for (int i = tid; i < 4096; i += 256) {
        float run = 0.f;
#pragma unroll
        for (int cc = 0; cc < NC; cc++) {
            float tv = S[cc * 4096 + i];
            S[cc * 4096 + i] = run;
            run += tv;
        }
    }
    if (tid < 64) {
        float* z = zc + (size_t)bh * NC * 64;
        float run = 0.f;
#pragma unroll
        for (int cc = 0; cc < NC; cc++) {
            float tv = z[cc * 64 + tid];
            z[cc * 64 + tid] = run;
            run += tv;
        }
    }
}

// ---------------- Phase C: per-chunk output + mini-LN ----------------
__global__ __launch_bounds__(256)
void phaseC_kernel(const float* __restrict__ qkv, const float* __restrict__ og,
                   const float* __restrict__ SU, const float* __restrict__ zc,
                   const float* __restrict__ mn_w, const float* __restrict__ mn_b,
                   float* __restrict__ attn) {
    int bid = blockIdx.x;           // bh*16 + c
    int bh = bid >> 4, c = bid & 15;
    int b = bh / Hc, h = bh % Hc;
    int tok0 = b * Lc + c * CH;
    __shared__ float Qs[64 * 65];   // q_f, padded (column reads)
    __shared__ float As[64 * 65];   // masked raw dots, padded (lane-l writes)
    __shared__ float Ks[64 * 64];   // k_f
    __shared__ float Vs[64 * 64];   // v * (1+g)
    __shared__ float zs[64];
    __shared__ float dens[64];
    __shared__ float denp[4][64];
    int tid = threadIdx.x;
    int lane = tid & 63, grp = tid >> 6;
#pragma unroll
    for (int i = 0; i < 16; i++) {
        int e2 = tid + i * 256;
        int tt = e2 >> 6, dd = e2 & 63;
        size_t rowoff = (size_t)(tok0 + tt) * TD + h * dh;
        float qv = qkv[rowoff + dd];
        float kv = qkv[rowoff + Dc + dd];
        float vv = qkv[rowoff + 2 * Dc + dd];
        float gv = og[(size_t)(tok0 + tt) * Hc + h];
        Qs[tt * 65 + dd] = qv > 0.f ? qv + 1.f : expf(qv);
        Ks[tt * 64 + dd] = kv > 0.f ? kv + 1.f : expf(kv);
        Vs[tt * 64 + dd] = vv * gv;
    }
    if (tid < 64) zs[tid] = zc[bid * 64 + tid];
    __syncthreads();

    // Step 1: raw masked dots A[l][t] = (q_f[l] . k_f[t]) for t<=l, else 0.
    // thread: l = lane, t in [grp*16, grp*16+16)
    int t0 = grp * 16;
    float dotp[16] = {};
    for (int d = 0; d < 64; d++) {
        float ql = Qs[lane * 65 + d];
#pragma unroll
        for (int j = 0; j < 16; j++)
            dotp[j] = fmaf(ql, Ks[(t0 + j) * 64 + d], dotp[j]);
    }
    float dsum = 0.f;
#pragma unroll
    for (int j = 0; j < 16; j++) {
        float dv = (t0 + j) <= lane ? dotp[j] : 0.f;
        As[lane * 65 + t0 + j] = dv;
        dsum += dv;
    }
    denp[grp][lane] = dsum;
    __syncthreads();

    // den[l] = q_f[l].z_start + sum_t<=l dot + 1e-6
    if (tid < 64) {
        int l = tid;
        float qz = 0.f;
        for (int d = 0; d < 64; d++) qz = fmaf(Qs[l * 65 + d], zs[d], qz);
        dens[l] = denp[0][l] + denp[1][l] + denp[2][l] + denp[3][l] + qz + 1e-6f;
    }
    __syncthreads();

    // Step 2: out_num[l][e] = sum_d Q[l][d]*S[d][e] + sum_t A[l][t]*Vog[t][e]
    // thread: e = lane, l in [grp*16, grp*16+16)
    const float* Sg = SU + (size_t)bid * 4096;
    int e = lane, l0 = grp * 16;
    float acc[16] = {};
    for (int d = 0; d < 64; d++) {
        float sv = Sg[d * 64 + e];
#pragma unroll
        for (int i = 0; i < 16; i++)
            acc[i] = fmaf(Qs[(l0 + i) * 65 + d], sv, acc[i]);
    }
    for (int t = 0; t < 64; t++) {
        float vv = Vs[t * 64 + e];
#pragma unroll
        for (int i = 0; i < 16; i++)
            acc[i] = fmaf(As[(l0 + i) * 65 + t], vv, acc[i]);
    }
    // divide by den, mini-LN over e (across the 64 lanes of this wave), store
    float mnw = mn_w[e], mnb = mn_b[e];
#pragma unroll
    for (int i = 0; i < 16; i++) {
        int l = l0 + i;
        float val = acc[i] / dens[l];
        float s = val;
#pragma unroll
        for (int m = 1; m < 64; m <<= 1) s += __shfl_xor(s, m, 64);
        float mu = s * (1.f / 64.f);
        float dv = val - mu;
        float s2 = dv * dv;
#pragma unroll
        for (int m = 1; m < 64; m <<= 1) s2 += __shfl_xor(s2, m, 64);
        float rstd = rsqrtf(s2 * (1.f / 64.f) + 1e-5f);
        attn[(size_t)(tok0 + l) * Dc + h * dh + e] = dv * rstd * mnw + mnb;
    }
}

extern "C" void kernel_launch(void* const* d_in, const int* in_sizes, int n_in,
                              void* d_out, int out_size, void* d_ws, size_t ws_size,
                              hipStream_t stream) {
    const float* x     = (const float*)d_in[0];
    const float* Wqkv  = (const float*)d_in[1];
    const float* bqkv  = (const float*)d_in[2];
    const float* Wb1   = (const float*)d_in[3];
    const float* Wb2   = (const float*)d_in[4];
    const float* temp  = (const float*)d_in[5];
    const float* Wproj = (const float*)d_in[6];
    const float* bproj = (const float*)d_in[7];
    const float* ln_w  = (const float*)d_in[8];
    const float* ln_b  = (const float*)d_in[9];
    const float* mn_w  = (const float*)d_in[10];
    const float* mn_b  = (const float*)d_in[11];

    float* out0 = (float*)d_out;                 // [2048, 768]
    float* gate = out0 + (size_t)BL * Dc;        // [2048, 12]

    float* ws   = (float*)d_ws;
    float* xn   = ws;                            // 2048*768
    float* qkv  = xn + (size_t)BL * Dc;          // 2048*2304
    float* tbuf = qkv + (size_t)BL * TD;         // 2048*128
    float* og   = tbuf + (size_t)BL * Rc;        // 2048*12
    float* SU   = og + (size_t)BL * Hc;          // 24*16*4096
    float* zc   = SU + (size_t)BH * NC * 4096;   // 24*16*64
    float* attn = zc + (size_t)BH * NC * 64;     // 2048*768

    // 1. LayerNorm
    ln_kernel<<<BL, 256, 0, stream>>>(x, ln_w, ln_b, xn);
    // 2. qkv = x_norm @ Wqkv + bqkv
    gemm_kernel<0><<<dim3(TD / 64, BL / 64), 256, 0, stream>>>(xn, Wqkv, bqkv, qkv, BL, TD, Dc);
    // 3. t = silu(x @ Wb1)   (raw x!)
    gemm_kernel<1><<<dim3(Rc / 64, BL / 64), 256, 0, stream>>>(x, Wb1, nullptr, tbuf, BL, Rc, Dc);
    // 4. gate + (1+gate)
    gate_kernel<<<BL * Hc / 256, 256, 0, stream>>>(tbuf, Wb2, temp, gate, og);
    // 5. per-chunk local KV state sums
    phaseA_kernel<<<BH * NC, 256, 0, stream>>>(qkv, og, SU, zc);
    // 6. exclusive prefix over chunks
    prefix_kernel<<<BH, 256, 0, stream>>>(SU, zc);
    // 7. per-chunk outputs + mini-LN
    phaseC_kernel<<<BH * NC, 256, 0, stream>>>(qkv, og, SU, zc, mn_w, mn_b, attn);
    // 8. out0 = attn @ Wproj + bproj
    gemm_kernel<0><<<dim3(Dc / 64, BL / 64), 256, 0, stream>>>(attn, Wproj, bproj, out0, BL, Dc, Dc);
}

// Round 2
// 237.755 us; speedup vs baseline: 1.2425x; 1.2425x over previous
//
#include <hip/hip_runtime.h>
#include <hip/hip_bf16.h>
#include <math.h>

// Problem constants
constexpr int Bc = 2, Lc = 1024, Dc = 768, Hc = 12, dh = 64, Rc = 128;
constexpr int BL = Bc * Lc;          // 2048 tokens
constexpr int TD = 3 * Dc;           // 2304
constexpr int CH = 64;               // chunk length
constexpr int NC = Lc / CH;          // 16 chunks per sequence
constexpr int BH = Bc * Hc;          // 24

typedef __attribute__((ext_vector_type(8))) short bf16x8;
typedef __attribute__((ext_vector_type(4))) float f32x4;

// ---------------- LayerNorm over D=768, bf16 output ----------------
__global__ __launch_bounds__(256)
void ln_kernel(const float* __restrict__ x, const float* __restrict__ w,
               const float* __restrict__ bcoef, __hip_bfloat16* __restrict__ y) {
    int row = blockIdx.x;
    const float* xr = x + (size_t)row * Dc;
    __hip_bfloat16* yr = y + (size_t)row * Dc;
    int tid = threadIdx.x;
    float v[3];
    float s = 0.f;
#pragma unroll
    for (int i = 0; i < 3; i++) { v[i] = xr[tid + i * 256]; s += v[i]; }
    __shared__ float red[256];
    red[tid] = s; __syncthreads();
    for (int off = 128; off > 0; off >>= 1) {
        if (tid < off) red[tid] += red[tid + off];
        __syncthreads();
    }
    float mu = red[0] / (float)Dc;
    __syncthreads();
    float s2 = 0.f;
#pragma unroll
    for (int i = 0; i < 3; i++) { float d = v[i] - mu; s2 += d * d; }
    red[tid] = s2; __syncthreads();
    for (int off = 128; off > 0; off >>= 1) {
        if (tid < off) red[tid] += red[tid + off];
        __syncthreads();
    }
    float rstd = rsqrtf(red[0] / (float)Dc + 1e-5f);
#pragma unroll
    for (int i = 0; i < 3; i++) {
        int c = tid + i * 256;
        yr[c] = __float2bfloat16((v[i] - mu) * rstd * w[c] + bcoef[c]);
    }
}

// ---------------- Transpose + fp32->bf16: W[K][N] -> WT[N][K] ----------------
__global__ __launch_bounds__(256)
void transpose_bf16_kernel(const float* __restrict__ W, __hip_bfloat16* __restrict__ WT,
                           int K, int N) {
    __shared__ float t[32][33];
    int k0 = blockIdx.y * 32, n0 = blockIdx.x * 32;
    int tid = threadIdx.x;
    int r = tid >> 5, c = tid & 31;   // r in 0..7
#pragma unroll
    for (int i = 0; i < 4; i++)
        t[r + i * 8][c] = W[(size_t)(k0 + r + i * 8) * N + n0 + c];
    __syncthreads();
#pragma unroll
    for (int i = 0; i < 4; i++)
        WT[(size_t)(n0 + r + i * 8) * K + k0 + c] = __float2bfloat16(t[c][r + i * 8]);
}

// ---------------- bf16 MFMA GEMM: C[M][N] = A[M][K] @ BT[N][K]^T + bias ----------------
// 128x128 tile, BK=64, 256 threads = 4 waves (2x2), 4x4 frags of 16x16x32 per wave.
constexpr int LDT = 72;   // bf16 elems per LDS row (64 + 8 pad) = 144B = 36 dwords
__global__ __launch_bounds__(256)
void gemm_bf16_kernel(const __hip_bfloat16* __restrict__ A,
                      const __hip_bfloat16* __restrict__ BT,
                      const float* __restrict__ bias,
                      float* __restrict__ C, int M, int N, int K) {
    __shared__ short As[128 * LDT];
    __shared__ short Bs[128 * LDT];
    int tid = threadIdx.x;
    int m0 = blockIdx.y * 128, n0 = blockIdx.x * 128;
    int wave = tid >> 6, lane = tid & 63;
    int wr = (wave >> 1) * 64, wc = (wave & 1) * 64;
    int l16 = lane & 15, l4 = lane >> 4;

    f32x4 acc[4][4];
#pragma unroll
    for (int i = 0; i < 4; i++)
#pragma unroll
        for (int j = 0; j < 4; j++)
            acc[i][j] = f32x4{0.f, 0.f, 0.f, 0.f};

    int slot = tid & 7;      // 16B chunk within a 128B row
    int row0 = tid >> 3;     // 0..31

    for (int k0 = 0; k0 < K; k0 += 64) {
        float4 av[4], bv[4];
#pragma unroll
        for (int i = 0; i < 4; i++) {
            int r = row0 + i * 32;
            av[i] = *reinterpret_cast<const float4*>(A  + (size_t)(m0 + r) * K + k0 + slot * 8);
            bv[i] = *reinterpret_cast<const float4*>(BT + (size_t)(n0 + r) * K + k0 + slot * 8);
        }
        __syncthreads();    // previous tile's ds_reads complete before overwrite
#pragma unroll
        for (int i = 0; i < 4; i++) {
            int r = row0 + i * 32;
            *reinterpret_cast<float4*>(&As[r * LDT + slot * 8]) = av[i];
            *reinterpret_cast<float4*>(&Bs[r * LDT + slot * 8]) = bv[i];
        }
        __syncthreads();
#pragma unroll
        for (int kk = 0; kk < 2; kk++) {
            bf16x8 af[4], bfr[4];
#pragma unroll
            for (int f = 0; f < 4; f++) {
                af[f]  = *reinterpret_cast<const bf16x8*>(&As[(wr + f * 16 + l16) * LDT + kk * 32 + l4 * 8]);
                bfr[f] = *reinterpret_cast<const bf16x8*>(&Bs[(wc + f * 16 + l16) * LDT + kk * 32 + l4 * 8]);
            }
#pragma unroll
            for (int i = 0; i < 4; i++)
#pragma unroll
                for (int j = 0; j < 4; j++)
                    acc[i][j] = __builtin_amdgcn_mfma_f32_16x16x32_bf16(af[i], bfr[j], acc[i][j], 0, 0, 0);
        }
    }
    int crow = l4 * 4;
#pragma unroll
    for (int i = 0; i < 4; i++) {
#pragma unroll
        for (int j = 0; j < 4; j++) {
            int col = n0 + wc + j * 16 + l16;
            float bb = bias ? bias[col] : 0.f;
#pragma unroll
            for (int r = 0; r < 4; r++) {
                int rowm = m0 + wr + i * 16 + crow + r;
                C[(size_t)rowm * N + col] = acc[i][j][r] + bb;
            }
        }
    }
}

// ---------------- Tiled fp32 GEMM (kept for the small bottleneck GEMM) ----------------
template <int ACT>
__global__ __launch_bounds__(256)
void gemm_kernel(const float* __restrict__ A, const float* __restrict__ W,
                 const float* __restrict__ bias, float* __restrict__ C,
                 int M, int N, int K) {
    __shared__ float As[16 * 68];
    __shared__ float Bs[16 * 64];
    int tid = threadIdx.x;
    int m0 = blockIdx.y * 64, n0 = blockIdx.x * 64;
    int tm = tid >> 4, tn = tid & 15;
    float acc[4][4] = {};
    for (int k0 = 0; k0 < K; k0 += 16) {
#pragma unroll
        for (int i = 0; i < 4; i++) {
            int e = tid + i * 256;
            int r = e >> 4, c = e & 15;
            As[c * 68 + r] = A[(size_t)(m0 + r) * K + k0 + c];
        }
#pragma unroll
        for (int i = 0; i < 4; i++) {
            int e = tid + i * 256;
            int r = e >> 6, c = e & 63;
            Bs[r * 64 + c] = W[(size_t)(k0 + r) * N + n0 + c];
        }
        __syncthreads();
#pragma unroll
        for (int k = 0; k < 16; k++) {
            float4 a4 = *reinterpret_cast<const float4*>(&As[k * 68 + tm * 4]);
            float4 b4 = *reinterpret_cast<const float4*>(&Bs[k * 64 + tn * 4]);
            float a[4] = {a4.x, a4.y, a4.z, a4.w};
            float b[4] = {b4.x, b4.y, b4.z, b4.w};
#pragma unroll
            for (int i = 0; i < 4; i++)
#pragma unroll
                for (int j = 0; j < 4; j++)
                    acc[i][j] = fmaf(a[i], b[j], acc[i][j]);
        }
        __syncthreads();
    }
#pragma unroll
    for (int i = 0; i < 4; i++) {
        int row = m0 + tm * 4 + i;
#pragma unroll
        for (int j = 0; j < 4; j++) {
            int col = n0 + tn * 4 + j;
            float v = acc[i][j];
            if (bias) v += bias[col];
            if (ACT == 1) v = v / (1.f + expf(-v));
            C[(size_t)row * N + col] = v;
        }
    }
}

// ---------------- Gate params ----------------
__global__ __launch_bounds__(256)
void gate_kernel(const float* __restrict__ tbuf, const float* __restrict__ Wb2,
                 const float* __restrict__ temperature,
                 float* __restrict__ gate_out, float* __restrict__ og) {
    int id = blockIdx.x * 256 + threadIdx.x;   // < 24576
    int tok = id / Hc, h = id % Hc;
    const float* tr = tbuf + (size_t)tok * Rc;
    float p[5] = {};
    for (int r = 0; r < Rc; r++) {
        float tv = tr[r];
        const float* wr = Wb2 + r * (Hc * 5) + h * 5;
#pragma unroll
        for (int c = 0; c < 5; c++) p[c] = fmaf(tv, wr[c], p[c]);
    }
    const float PI = 3.14159265358979323846f;
    float sem_amp = 1.f / (1.f + expf(-p[0]));
    float sem_phase = tanhf(p[1]) * PI;
    float ctx_amp = 1.f / (1.f + expf(-p[2]));
    float ctx_phase = tanhf(p[3]) * PI;
    float temp = fminf(fmaxf(temperature[0], 0.1f), 2.0f);
    float inter = tanhf(sem_amp * ctx_amp * cosf(sem_phase - ctx_phase)) * temp;
    float g = 1.f / (1.f + expf(-inter));
    gate_out[id] = g;
    og[id] = 1.f + g;
}

// ---------------- Phase A: per-chunk U_c = K^T diag(1+g) V, zc = sum K ----------------
__global__ __launch_bounds__(256)
void phaseA_kernel(const float* __restrict__ qkv, const float* __restrict__ og,
                   float* __restrict__ SU, float* __restrict__ zc) {
    int bid = blockIdx.x;           // bh*16 + c
    int bh = bid >> 4, c = bid & 15;
    int b = bh / Hc, h = bh % Hc;
    int tok0 = b * Lc + c * CH;
    __shared__ float Ks[64 * 64];
    __shared__ float Vs[64 * 64];
    int tid = threadIdx.x;
#pragma unroll
    for (int i = 0; i < 16; i++) {
        int e2 = tid + i * 256;
        int tt = e2 >> 6, dd = e2 & 63;
        size_t rowoff = (size_t)(tok0 + tt) * TD + h * dh;
        float kv = qkv[rowoff + Dc + dd];
        float vv = qkv[rowoff + 2 * Dc + dd];
        float gv = og[(size_t)(tok0 + tt) * Hc + h];
        Ks[tt * 64 + dd] = kv > 0.f ? kv + 1.f : expf(kv);
        Vs[tt * 64 + dd] = vv * gv;
    }
    __syncthreads();
    int e = tid & 63, d0 = (tid >> 6) * 16;
    float u[16] = {};
    for (int tt = 0; tt < 64; tt++) {
        float vv = Vs[tt * 64 + e];
#pragma unroll
        for (int j = 0; j < 16; j++)
            u[j] = fmaf(Ks[tt * 64 + d0 + j], vv, u[j]);
    }
    float* Uo = SU + (size_t)bid * 4096;
#pragma unroll
    for (int j = 0; j < 16; j++)
        Uo[(d0 + j) * 64 + e] = u[j];
    if (tid < 64) {
        float zsum = 0.f;
        for (int tt = 0; tt < 64; tt++) zsum += Ks[tt * 64 + tid];
        zc[bid * 64 + tid] = zsum;
    }
}

// ---------------- Phase B: exclusive prefix over chunks (in place) ----------------
__global__ __launch_bounds__(256)
void prefix_kernel(float* __restrict__ SU, float* __restrict__ zc) {
    int bh = blockIdx.x;
    int tid = threadIdx.x;
    float* S = SU + (size_t)bh * NC * 4096;
    for (int i = tid; i < 4096; i += 256) {
        float run = 0.f;
#pragma unroll
        for (int cc = 0; cc < NC; cc++) {
            float tv = S[cc * 4096 + i];
            S[cc * 4096 + i] = run;
            run += tv;
        }
    }
    if (tid < 64) {
        float* z = zc + (size_t)bh * NC * 64;
        float run = 0.f;
#pragma unroll
        for (int cc = 0; cc < NC; cc++) {
            float tv = z[cc * 64 + tid];
            z[cc * 64 + tid] = run;
            run += tv;
        }
    }
}

// ---------------- Phase C: per-chunk output + mini-LN, bf16 out ----------------
__global__ __launch_bounds__(256)
void phaseC_kernel(const float* __restrict__ qkv, const float* __restrict__ og,
                   const float* __restrict__ SU, const float* __restrict__ zc,
                   const float* __restrict__ mn_w, const float* __restrict__ mn_b,
                   __hip_bfloat16* __restrict__ attn) {
    int bid = blockIdx.x;           // bh*16 + c
    int bh = bid >> 4, c = bid & 15;
    int b = bh / Hc, h = bh % Hc;
    int tok0 = b * Lc + c * CH;
    __shared__ float Qs[64 * 65];
    __shared__ float As[64 * 65];
    __shared__ float Ks[64 * 64];
    __shared__ float Vs[64 * 64];
    __shared__ float zs[64];
    __shared__ float dens[64];
    __shared__ float denp[4][64];
    int tid = threadIdx.x;
    int lane = tid & 63, grp = tid >> 6;
#pragma unroll
    for (int i = 0; i < 16; i++) {
        int e2 = tid + i * 256;
        int tt = e2 >> 6, dd = e2 & 63;
        size_t rowoff = (size_t)(tok0 + tt) * TD + h * dh;
        float qv = qkv[rowoff + dd];
        float kv = qkv[rowoff + Dc + dd];
        float vv = qkv[rowoff + 2 * Dc + dd];
        float gv = og[(size_t)(tok0 + tt) * Hc + h];
        Qs[tt * 65 + dd] = qv > 0.f ? qv + 1.f : expf(qv);
        Ks[tt * 64 + dd] = kv > 0.f ? kv + 1.f : expf(kv);
        Vs[tt * 64 + dd] = vv * gv;
    }
    if (tid < 64) zs[tid] = zc[bid * 64 + tid];
    __syncthreads();

    int t0 = grp * 16;
    float dotp[16] = {};
    for (int d = 0; d < 64; d++) {
        float ql = Qs[lane * 65 + d];
#pragma unroll
        for (int j = 0; j < 16; j++)
            dotp[j] = fmaf(ql, Ks[(t0 + j) * 64 + d], dotp[j]);
    }
    float dsum = 0.f;
#pragma unroll
    for (int j = 0; j < 16; j++) {
        float dv = (t0 + j) <= lane ? dotp[j] : 0.f;
        As[lane * 65 + t0 + j] = dv;
        dsum += dv;
    }
    denp[grp][lane] = dsum;
    __syncthreads();

    if (tid < 64) {
        int l = tid;
        float qz = 0.f;
        for (int d = 0; d < 64; d++) qz = fmaf(Qs[l * 65 + d], zs[d], qz);
        dens[l] = denp[0][l] + denp[1][l] + denp[2][l] + denp[3][l] + qz + 1e-6f;
    }
    __syncthreads();

    const float* Sg = SU + (size_t)bid * 4096;
    int e = lane, l0 = grp * 16;
    float acc[16] = {};
    for (int d = 0; d < 64; d++) {
        float sv = Sg[d * 64 + e];
#pragma unroll
        for (int i = 0; i < 16; i++)
            acc[i] = fmaf(Qs[(l0 + i) * 65 + d], sv, acc[i]);
    }
    for (int t = 0; t < 64; t++) {
        float vv = Vs[t * 64 + e];
#pragma unroll
        for (int i = 0; i < 16; i++)
            acc[i] = fmaf(As[(l0 + i) * 65 + t], vv, acc[i]);
    }
    float mnw = mn_w[e], mnb = mn_b[e];
#pragma unroll
    for (int i = 0; i < 16; i++) {
        int l = l0 + i;
        float val = acc[i] / dens[l];
        float s = val;
#pragma unroll
        for (int m = 1; m < 64; m <<= 1) s += __shfl_xor(s, m, 64);
        float mu = s * (1.f / 64.f);
        float dv = val - mu;
        float s2 = dv * dv;
#pragma unroll
        for (int m = 1; m < 64; m <<= 1) s2 += __shfl_xor(s2, m, 64);
        float rstd = rsqrtf(s2 * (1.f / 64.f) + 1e-5f);
        attn[(size_t)(tok0 + l) * Dc + h * dh + e] = __float2bfloat16(dv * rstd * mnw + mnb);
    }
}

extern "C" void kernel_launch(void* const* d_in, const int* in_sizes, int n_in,
                              void* d_out, int out_size, void* d_ws, size_t ws_size,
                              hipStream_t stream) {
    const float* x     = (const float*)d_in[0];
    const float* Wqkv  = (const float*)d_in[1];
    const float* bqkv  = (const float*)d_in[2];
    const float* Wb1   = (const float*)d_in[3];
    const float* Wb2   = (const float*)d_in[4];
    const float* temp  = (const float*)d_in[5];
    const float* Wproj = (const float*)d_in[6];
    const float* bproj = (const float*)d_in[7];
    const float* ln_w  = (const float*)d_in[8];
    const float* ln_b  = (const float*)d_in[9];
    const float* mn_w  = (const float*)d_in[10];
    const float* mn_b  = (const float*)d_in[11];

    float* out0 = (float*)d_out;                 // [2048, 768]
    float* gate = out0 + (size_t)BL * Dc;        // [2048, 12]

    float* ws   = (float*)d_ws;
    float* qkv  = ws;                            // 2048*2304 f
    float* tbuf = qkv + (size_t)BL * TD;         // 2048*128 f
    float* og   = tbuf + (size_t)BL * Rc;        // 2048*12 f
    float* SU   = og + (size_t)BL * Hc;          // 24*16*4096 f
    float* zc   = SU + (size_t)BH * NC * 4096;   // 24*16*64 f
    __hip_bfloat16* bfr = (__hip_bfloat16*)(zc + (size_t)BH * NC * 64);
    __hip_bfloat16* xnb    = bfr;                        // 2048*768 bf16
    __hip_bfloat16* attnb  = xnb + (size_t)BL * Dc;      // 2048*768 bf16
    __hip_bfloat16* WqkvT  = attnb + (size_t)BL * Dc;    // 2304*768 bf16
    __hip_bfloat16* WprojT = WqkvT + (size_t)TD * Dc;    // 768*768 bf16

    // 0. weight transposes -> bf16 [N][K]
    transpose_bf16_kernel<<<dim3(TD / 32, Dc / 32), 256, 0, stream>>>(Wqkv, WqkvT, Dc, TD);
    transpose_bf16_kernel<<<dim3(Dc / 32, Dc / 32), 256, 0, stream>>>(Wproj, WprojT, Dc, Dc);
    // 1. LayerNorm -> bf16
    ln_kernel<<<BL, 256, 0, stream>>>(x, ln_w, ln_b, xnb);
    // 2. qkv = x_norm @ Wqkv + bqkv   (bf16 MFMA)
    gemm_bf16_kernel<<<dim3(TD / 128, BL / 128), 256, 0, stream>>>(xnb, WqkvT, bqkv, qkv, BL, TD, Dc);
    // 3. t = silu(x @ Wb1)   (raw x, fp32)
    gemm_kernel<1><<<dim3(Rc / 64, BL / 64), 256, 0, stream>>>(x, Wb1, nullptr, tbuf, BL, Rc, Dc);
    // 4. gate + (1+gate)
    gate_kernel<<<BL * Hc / 256, 256, 0, stream>>>(tbuf, Wb2, temp, gate, og);
    // 5. per-chunk local KV state sums
    phaseA_kernel<<<BH * NC, 256, 0, stream>>>(qkv, og, SU, zc);
    // 6. exclusive prefix over chunks
    prefix_kernel<<<BH, 256, 0, stream>>>(SU, zc);
    // 7. per-chunk outputs + mini-LN -> bf16
    phaseC_kernel<<<BH * NC, 256, 0, stream>>>(qkv, og, SU, zc, mn_w, mn_b, attnb);
    // 8. out0 = attn @ Wproj + bproj  (bf16 MFMA)
    gemm_bf16_kernel<<<dim3(Dc / 128, BL / 128), 256, 0, stream>>>(attnb, WprojT, bproj, out0, BL, Dc, Dc);
}

// Round 3
// 161.637 us; speedup vs baseline: 1.8276x; 1.4709x over previous
//
#include <hip/hip_runtime.h>
#include <hip/hip_bf16.h>
#include <math.h>

// Problem constants
constexpr int Bc = 2, Lc = 1024, Dc = 768, Hc = 12, dh = 64, Rc = 128;
constexpr int BL = Bc * Lc;          // 2048 tokens
constexpr int TD = 3 * Dc;           // 2304
constexpr int CH = 64;               // chunk length
constexpr int NC = Lc / CH;          // 16 chunks per sequence
constexpr int BH = Bc * Hc;          // 24

typedef __attribute__((ext_vector_type(8))) short bf16x8;
typedef __attribute__((ext_vector_type(4))) float f32x4;

__device__ __forceinline__ float bf2f(short u) {
    union { float f; unsigned int i; } c;
    c.i = ((unsigned int)(unsigned short)u) << 16;
    return c.f;
}

#define GLOAD_LDS16(gp, lp)                                                        \
    __builtin_amdgcn_global_load_lds(                                              \
        (const __attribute__((address_space(1))) void*)(gp),                       \
        (__attribute__((address_space(3))) void*)(lp), 16, 0, 0)

// ---------------- LayerNorm over D=768, bf16 output ----------------
__global__ __launch_bounds__(256)
void ln_kernel(const float* __restrict__ x, const float* __restrict__ w,
               const float* __restrict__ bcoef, __hip_bfloat16* __restrict__ y) {
    int row = blockIdx.x;
    const float* xr = x + (size_t)row * Dc;
    __hip_bfloat16* yr = y + (size_t)row * Dc;
    int tid = threadIdx.x;
    float v[3];
    float s = 0.f;
#pragma unroll
    for (int i = 0; i < 3; i++) { v[i] = xr[tid + i * 256]; s += v[i]; }
    __shared__ float red[256];
    red[tid] = s; __syncthreads();
    for (int off = 128; off > 0; off >>= 1) {
        if (tid < off) red[tid] += red[tid + off];
        __syncthreads();
    }
    float mu = red[0] / (float)Dc;
    __syncthreads();
    float s2 = 0.f;
#pragma unroll
    for (int i = 0; i < 3; i++) { float d = v[i] - mu; s2 += d * d; }
    red[tid] = s2; __syncthreads();
    for (int off = 128; off > 0; off >>= 1) {
        if (tid < off) red[tid] += red[tid + off];
        __syncthreads();
    }
    float rstd = rsqrtf(red[0] / (float)Dc + 1e-5f);
#pragma unroll
    for (int i = 0; i < 3; i++) {
        int c = tid + i * 256;
        yr[c] = __float2bfloat16((v[i] - mu) * rstd * w[c] + bcoef[c]);
    }
}

// ---------------- Transpose + fp32->bf16: W[K][N] -> WT[N][K] ----------------
__global__ __launch_bounds__(256)
void transpose_bf16_kernel(const float* __restrict__ W, __hip_bfloat16* __restrict__ WT,
                           int K, int N) {
    __shared__ float t[32][33];
    int k0 = blockIdx.y * 32, n0 = blockIdx.x * 32;
    int tid = threadIdx.x;
    int r = tid >> 5, c = tid & 31;   // r in 0..7
#pragma unroll
    for (int i = 0; i < 4; i++)
        t[r + i * 8][c] = W[(size_t)(k0 + r + i * 8) * N + n0 + c];
    __syncthreads();
#pragma unroll
    for (int i = 0; i < 4; i++)
        WT[(size_t)(n0 + r + i * 8) * K + k0 + c] = __float2bfloat16(t[c][r + i * 8]);
}

// ---------------- bf16 MFMA GEMM, 2-phase global_load_lds pipeline ----------------
// C[M][N] = A[M][K] @ BT[N][K]^T + bias. 128x128 tile, BK=64, 512 thr = 8 waves.
// LDS: 2 buffers x (A 128x64 + B 128x64) bf16 = 64 KB. Linear rows (128 B) with
// XOR slot swizzle applied on BOTH the global source and the ds_read (rule #21).
template <bool OUT_BF16>
__global__ __launch_bounds__(512)
void gemm_mfma_kernel(const __hip_bfloat16* __restrict__ A,
                      const __hip_bfloat16* __restrict__ BT,
                      const float* __restrict__ bias,
                      void* __restrict__ Cout, int M, int N, int K) {
    __shared__ short lds[2][2][128 * 64];   // [buf][A/B][row*64 + elem]
    int tid = threadIdx.x;
    int wave = tid >> 6, lane = tid & 63;
    int l16 = lane & 15, l4 = lane >> 4;
    int m0 = blockIdx.y * 128, n0 = blockIdx.x * 128;

    // --- staging role: waves 0-3 stage A rows, waves 4-7 stage B rows ---
    int ab = wave >> 2;                       // 0 = A, 1 = B
    int r_in = lane >> 3;                     // 0..7 row within 8-row group
    int s_src = (lane & 7) ^ r_in;            // inverse-swizzled source slot
    const __hip_bfloat16* gbase = ab ? (BT + (size_t)n0 * K) : (A + (size_t)m0 * K);
    const __hip_bfloat16* gsrc =
        gbase + (size_t)((wave & 3) * 32 + r_in) * K + s_src * 8;

    // --- compute role: wave (wr, wc) owns 64x32 of C; frags 4(M) x 2(N) ---
    int wr = (wave >> 2) * 64, wc = (wave & 3) * 32;
    int xs = l16 & 7;                         // read-side XOR (== row & 7)

    f32x4 acc[4][2];
#pragma unroll
    for (int i = 0; i < 4; i++)
#pragma unroll
        for (int j = 0; j < 2; j++) acc[i][j] = f32x4{0.f, 0.f, 0.f, 0.f};

    auto stage = [&](int buf, int kt) {
        const __hip_bfloat16* g = gsrc + kt * 64;
        short* lb = &lds[buf][ab][(wave & 3) * 32 * 64];
#pragma unroll
        for (int i = 0; i < 4; i++)           // each instr: 8 rows x 1 KB
            GLOAD_LDS16(g + (size_t)i * 8 * K, lb + i * 8 * 64);
    };

    auto compute = [&](int buf) {
        const short* As = &lds[buf][0][0];
        const short* Bs = &lds[buf][1][0];
#pragma unroll
        for (int kk = 0; kk < 2; kk++) {
            bf16x8 af[4], bfr[2];
            int slot = (kk * 4 + l4) ^ xs;
#pragma unroll
            for (int f = 0; f < 4; f++)
                af[f] = *reinterpret_cast<const bf16x8*>(
                    &As[(wr + f * 16 + l16) * 64 + slot * 8]);
#pragma unroll
            for (int f = 0; f < 2; f++)
                bfr[f] = *reinterpret_cast<const bf16x8*>(
                    &Bs[(wc + f * 16 + l16) * 64 + slot * 8]);
#pragma unroll
            for (int i = 0; i < 4; i++)
#pragma unroll
                for (int j = 0; j < 2; j++)
                    acc[i][j] = __builtin_amdgcn_mfma_f32_16x16x32_bf16(
                        af[i], bfr[j], acc[i][j], 0, 0, 0);
        }
    };

    int NT = K / 64;
    int cur = 0;
    stage(0, 0);
    __syncthreads();                          // drains vmcnt(0): buf0 ready
    for (int t = 0; t < NT; t++) {
        if (t + 1 < NT) stage(cur ^ 1, t + 1);   // async, overlaps MFMA below
        compute(cur);
        if (t + 1 < NT) { __syncthreads(); cur ^= 1; }
    }

    int crow = l4 * 4;
#pragma unroll
    for (int i = 0; i < 4; i++) {
#pragma unroll
        for (int j = 0; j < 2; j++) {
            int col = n0 + wc + j * 16 + l16;
            float bb = bias[col];
#pragma unroll
            for (int r = 0; r < 4; r++) {
                int rowm = m0 + wr + i * 16 + crow + r;
                float v = acc[i][j][r] + bb;
                if (OUT_BF16)
                    ((__hip_bfloat16*)Cout)[(size_t)rowm * N + col] = __float2bfloat16(v);
                else
                    ((float*)Cout)[(size_t)rowm * N + col] = v;
            }
        }
    }
}

// ---------------- Tiled fp32 GEMM (kept for the small bottleneck GEMM) ----------------
template <int ACT>
__global__ __launch_bounds__(256)
void gemm_kernel(const float* __restrict__ A, const float* __restrict__ W,
                 const float* __restrict__ bias, float* __restrict__ C,
                 int M, int N, int K) {
    __shared__ float As[16 * 68];
    __shared__ float Bs[16 * 64];
    int tid = threadIdx.x;
    int m0 = blockIdx.y * 64, n0 = blockIdx.x * 64;
    int tm = tid >> 4, tn = tid & 15;
    float acc[4][4] = {};
    for (int k0 = 0; k0 < K; k0 += 16) {
#pragma unroll
        for (int i = 0; i < 4; i++) {
            int e = tid + i * 256;
            int r = e >> 4, c = e & 15;
            As[c * 68 + r] = A[(size_t)(m0 + r) * K + k0 + c];
        }
#pragma unroll
        for (int i = 0; i < 4; i++) {
            int e = tid + i * 256;
            int r = e >> 6, c = e & 63;
            Bs[r * 64 + c] = W[(size_t)(k0 + r) * N + n0 + c];
        }
        __syncthreads();
#pragma unroll
        for (int k = 0; k < 16; k++) {
            float4 a4 = *reinterpret_cast<const float4*>(&As[k * 68 + tm * 4]);
            float4 b4 = *reinterpret_cast<const float4*>(&Bs[k * 64 + tn * 4]);
            float a[4] = {a4.x, a4.y, a4.z, a4.w};
            float b[4] = {b4.x, b4.y, b4.z, b4.w};
#pragma unroll
            for (int i = 0; i < 4; i++)
#pragma unroll
                for (int j = 0; j < 4; j++)
                    acc[i][j] = fmaf(a[i], b[j], acc[i][j]);
        }
        __syncthreads();
    }
#pragma unroll
    for (int i = 0; i < 4; i++) {
        int row = m0 + tm * 4 + i;
#pragma unroll
        for (int j = 0; j < 4; j++) {
            int col = n0 + tn * 4 + j;
            float v = acc[i][j];
            if (bias) v += bias[col];
            if (ACT == 1) v = v / (1.f + expf(-v));
            C[(size_t)row * N + col] = v;
        }
    }
}

// ---------------- Gate params ----------------
__global__ __launch_bounds__(256)
void gate_kernel(const float* __restrict__ tbuf, const float* __restrict__ Wb2,
                 const float* __restrict__ temperature,
                 float* __restrict__ gate_out, float* __restrict__ og) {
    int id = blockIdx.x * 256 + threadIdx.x;   // < 24576
    int tok = id / Hc, h = id % Hc;
    const float* tr = tbuf + (size_t)tok * Rc;
    float p[5] = {};
    for (int r = 0; r < Rc; r++) {
        float tv = tr[r];
        const float* wr = Wb2 + r * (Hc * 5) + h * 5;
#pragma unroll
        for (int c = 0; c < 5; c++) p[c] = fmaf(tv, wr[c], p[c]);
    }
    const float PI = 3.14159265358979323846f;
    float sem_amp = 1.f / (1.f + expf(-p[0]));
    float sem_phase = tanhf(p[1]) * PI;
    float ctx_amp = 1.f / (1.f + expf(-p[2]));
    float ctx_phase = tanhf(p[3]) * PI;
    float temp = fminf(fmaxf(temperature[0], 0.1f), 2.0f);
    float inter = tanhf(sem_amp * ctx_amp * cosf(sem_phase - ctx_phase)) * temp;
    float g = 1.f / (1.f + expf(-inter));
    gate_out[id] = g;
    og[id] = 1.f + g;
}

// ---------------- Phase A: per-chunk U_c = K^T diag(1+g) V, zc = sum K ----------------
__global__ __launch_bounds__(256)
void phaseA_kernel(const __hip_bfloat16* __restrict__ qkv, const float* __restrict__ og,
                   float* __restrict__ SU, float* __restrict__ zc) {
    int bid = blockIdx.x;           // bh*16 + c
    int bh = bid >> 4, c = bid & 15;
    int b = bh / Hc, h = bh % Hc;
    int tok0 = b * Lc + c * CH;
    __shared__ float Ks[64 * 64];
    __shared__ float Vs[64 * 64];
    int tid = threadIdx.x;
#pragma unroll
    for (int i = 0; i < 2; i++) {
        int c8 = tid + i * 256;              // 16B chunk id, 0..511
        int tt = c8 >> 3, d8 = (c8 & 7) * 8;
        size_t rowoff = (size_t)(tok0 + tt) * TD + h * dh;
        bf16x8 k8 = *reinterpret_cast<const bf16x8*>(qkv + rowoff + Dc + d8);
        bf16x8 v8 = *reinterpret_cast<const bf16x8*>(qkv + rowoff + 2 * Dc + d8);
        float gv = og[(size_t)(tok0 + tt) * Hc + h];
        float kf[8], vf[8];
#pragma unroll
        for (int j = 0; j < 8; j++) {
            float kv = bf2f(k8[j]);
            kf[j] = kv > 0.f ? kv + 1.f : expf(kv);
            vf[j] = bf2f(v8[j]) * gv;
        }
        *reinterpret_cast<float4*>(&Ks[tt * 64 + d8])     = *reinterpret_cast<float4*>(&kf[0]);
        *reinterpret_cast<float4*>(&Ks[tt * 64 + d8 + 4]) = *reinterpret_cast<float4*>(&kf[4]);
        *reinterpret_cast<float4*>(&Vs[tt * 64 + d8])     = *reinterpret_cast<float4*>(&vf[0]);
        *reinterpret_cast<float4*>(&Vs[tt * 64 + d8 + 4]) = *reinterpret_cast<float4*>(&vf[4]);
    }
    __syncthreads();
    int e = tid & 63, d0 = (tid >> 6) * 16;
    float u[16] = {};
    for (int tt = 0; tt < 64; tt++) {
        float vv = Vs[tt * 64 + e];
#pragma unroll
        for (int j = 0; j < 16; j++)
            u[j] = fmaf(Ks[tt * 64 + d0 + j], vv, u[j]);
    }
    float* Uo = SU + (size_t)bid * 4096;
#pragma unroll
    for (int j = 0; j < 16; j++)
        Uo[(d0 + j) * 64 + e] = u[j];
    if (tid < 64) {
        float zsum = 0.f;
        for (int tt = 0; tt < 64; tt++) zsum += Ks[tt * 64 + tid];
        zc[bid * 64 + tid] = zsum;
    }
}

// ---------------- Phase B: exclusive prefix over chunks (in place) ----------------
__global__ __launch_bounds__(256)
void prefix_kernel(float* __restrict__ SU, float* __restrict__ zc) {
    int bh = blockIdx.x;
    int tid = threadIdx.x;
    float* S = SU + (size_t)bh * NC * 4096;
    for (int i = tid; i < 4096; i += 256) {
        float run = 0.f;
#pragma unroll
        for (int cc = 0; cc < NC; cc++) {
            float tv = S[cc * 4096 + i];
            S[cc * 4096 + i] = run;
            run += tv;
        }
    }
    if (tid < 64) {
        float* z = zc + (size_t)bh * NC * 64;
        float run = 0.f;
#pragma unroll
        for (int cc = 0; cc < NC; cc++) {
            float tv = z[cc * 64 + tid];
            z[cc * 64 + tid] = run;
            run += tv;
        }
    }
}

// ---------------- Phase C: per-chunk output + mini-LN, bf16 out ----------------
__global__ __launch_bounds__(256)
void phaseC_kernel(const __hip_bfloat16* __restrict__ qkv, const float* __restrict__ og,
                   const float* __restrict__ SU, const float* __restrict__ zc,
                   const float* __restrict__ mn_w, const float* __restrict__ mn_b,
                   __hip_bfloat16* __restrict__ attn) {
    int bid = blockIdx.x;           // bh*16 + c
    int bh = bid >> 4, c = bid & 15;
    int b = bh / Hc, h = bh % Hc;
    int tok0 = b * Lc + c * CH;
    __shared__ float Qs[64 * 65];
    __shared__ float As[64 * 65];
    __shared__ float Ks[64 * 64];
    __shared__ float Vs[64 * 64];
    __shared__ float zs[64];
    __shared__ float dens[64];
    __shared__ float denp[4][64];
    int tid = threadIdx.x;
    int lane = tid & 63, grp = tid >> 6;
#pragma unroll
    for (int i = 0; i < 2; i++) {
        int c8 = tid + i * 256;
        int tt = c8 >> 3, d8 = (c8 & 7) * 8;
        size_t rowoff = (size_t)(tok0 + tt) * TD + h * dh;
        bf16x8 q8 = *reinterpret_cast<const bf16x8*>(qkv + rowoff + d8);
        bf16x8 k8 = *reinterpret_cast<const bf16x8*>(qkv + rowoff + Dc + d8);
        bf16x8 v8 = *reinterpret_cast<const bf16x8*>(qkv + rowoff + 2 * Dc + d8);
        float gv = og[(size_t)(tok0 + tt) * Hc + h];
        float kf[8], vf[8];
#pragma unroll
        for (int j = 0; j < 8; j++) {
            float qv = bf2f(q8[j]);
            Qs[tt * 65 + d8 + j] = qv > 0.f ? qv + 1.f : expf(qv);
            float kv = bf2f(k8[j]);
            kf[j] = kv > 0.f ? kv + 1.f : expf(kv);
            vf[j] = bf2f(v8[j]) * gv;
        }
        *reinterpret_cast<float4*>(&Ks[tt * 64 + d8])     = *reinterpret_cast<float4*>(&kf[0]);
        *reinterpret_cast<float4*>(&Ks[tt * 64 + d8 + 4]) = *reinterpret_cast<float4*>(&kf[4]);
        *reinterpret_cast<float4*>(&Vs[tt * 64 + d8])     = *reinterpret_cast<float4*>(&vf[0]);
        *reinterpret_cast<float4*>(&Vs[tt * 64 + d8 + 4]) = *reinterpret_cast<float4*>(&vf[4]);
    }
    if (tid < 64) zs[tid] = zc[bid * 64 + tid];
    __syncthreads();

    int t0 = grp * 16;
    float dotp[16] = {};
    for (int d = 0; d < 64; d++) {
        float ql = Qs[lane * 65 + d];
#pragma unroll
        for (int j = 0; j < 16; j++)
            dotp[j] = fmaf(ql, Ks[(t0 + j) * 64 + d], dotp[j]);
    }
    float dsum = 0.f;
#pragma unroll
    for (int j = 0; j < 16; j++) {
        float dv = (t0 + j) <= lane ? dotp[j] : 0.f;
        As[lane * 65 + t0 + j] = dv;
        dsum += dv;
    }
    denp[grp][lane] = dsum;
    __syncthreads();

    if (tid < 64) {
        int l = tid;
        float qz = 0.f;
        for (int d = 0; d < 64; d++) qz = fmaf(Qs[l * 65 + d], zs[d], qz);
        dens[l] = denp[0][l] + denp[1][l] + denp[2][l] + denp[3][l] + qz + 1e-6f;
    }
    __syncthreads();

    const float* Sg = SU + (size_t)bid * 4096;
    int e = lane, l0 = grp * 16;
    float acc[16] = {};
    for (int d = 0; d < 64; d++) {
        float sv = Sg[d * 64 + e];
#pragma unroll
        for (int i = 0; i < 16; i++)
            acc[i] = fmaf(Qs[(l0 + i) * 65 + d], sv, acc[i]);
    }
    for (int t = 0; t < 64; t++) {
        float vv = Vs[t * 64 + e];
#pragma unroll
        for (int i = 0; i < 16; i++)
            acc[i] = fmaf(As[(l0 + i) * 65 + t], vv, acc[i]);
    }
    float mnw = mn_w[e], mnb = mn_b[e];
#pragma unroll
    for (int i = 0; i < 16; i++) {
        int l = l0 + i;
        float val = acc[i] / dens[l];
        float s = val;
#pragma unroll
        for (int m = 1; m < 64; m <<= 1) s += __shfl_xor(s, m, 64);
        float mu = s * (1.f / 64.f);
        float dv = val - mu;
        float s2 = dv * dv;
#pragma unroll
        for (int m = 1; m < 64; m <<= 1) s2 += __shfl_xor(s2, m, 64);
        float rstd = rsqrtf(s2 * (1.f / 64.f) + 1e-5f);
        attn[(size_t)(tok0 + l) * Dc + h * dh + e] = __float2bfloat16(dv * rstd * mnw + mnb);
    }
}

extern "C" void kernel_launch(void* const* d_in, const int* in_sizes, int n_in,
                              void* d_out, int out_size, void* d_ws, size_t ws_size,
                              hipStream_t stream) {
    const float* x     = (const float*)d_in[0];
    const float* Wqkv  = (const float*)d_in[1];
    const float* bqkv  = (const float*)d_in[2];
    const float* Wb1   = (const float*)d_in[3];
    const float* Wb2   = (const float*)d_in[4];
    const float* temp  = (const float*)d_in[5];
    const float* Wproj = (const float*)d_in[6];
    const float* bproj = (const float*)d_in[7];
    const float* ln_w  = (const float*)d_in[8];
    const float* ln_b  = (const float*)d_in[9];
    const float* mn_w  = (const float*)d_in[10];
    const float* mn_b  = (const float*)d_in[11];

    float* out0 = (float*)d_out;                 // [2048, 768]
    float* gate = out0 + (size_t)BL * Dc;        // [2048, 12]

    float* ws   = (float*)d_ws;
    float* tbuf = ws;                            // 2048*128 f32
    float* og   = tbuf + (size_t)BL * Rc;        // 2048*12 f32
    float* SU   = og + (size_t)BL * Hc;          // 24*16*4096 f32
    float* zc   = SU + (size_t)BH * NC * 4096;   // 24*16*64 f32
    __hip_bfloat16* bfr = (__hip_bfloat16*)(zc + (size_t)BH * NC * 64);
    __hip_bfloat16* qkvb   = bfr;                        // 2048*2304 bf16
    __hip_bfloat16* xnb    = qkvb + (size_t)BL * TD;     // 2048*768 bf16
    __hip_bfloat16* attnb  = xnb + (size_t)BL * Dc;      // 2048*768 bf16
    __hip_bfloat16* WqkvT  = attnb + (size_t)BL * Dc;    // 2304*768 bf16
    __hip_bfloat16* WprojT = WqkvT + (size_t)TD * Dc;    // 768*768 bf16

    // 0. weight transposes -> bf16 [N][K]
    transpose_bf16_kernel<<<dim3(TD / 32, Dc / 32), 256, 0, stream>>>(Wqkv, WqkvT, Dc, TD);
    transpose_bf16_kernel<<<dim3(Dc / 32, Dc / 32), 256, 0, stream>>>(Wproj, WprojT, Dc, Dc);
    // 1. LayerNorm -> bf16
    ln_kernel<<<BL, 256, 0, stream>>>(x, ln_w, ln_b, xnb);
    // 2. qkv = x_norm @ Wqkv + bqkv   (bf16 MFMA, 2-phase pipeline, bf16 out)
    gemm_mfma_kernel<true><<<dim3(TD / 128, BL / 128), 512, 0, stream>>>(
        xnb, WqkvT, bqkv, qkvb, BL, TD, Dc);
    // 3. t = silu(x @ Wb1)   (raw x, fp32)
    gemm_kernel<1><<<dim3(Rc / 64, BL / 64), 256, 0, stream>>>(x, Wb1, nullptr, tbuf, BL, Rc, Dc);
    // 4. gate + (1+gate)
    gate_kernel<<<BL * Hc / 256, 256, 0, stream>>>(tbuf, Wb2, temp, gate, og);
    // 5. per-chunk local KV state sums
    phaseA_kernel<<<BH * NC, 256, 0, stream>>>(qkvb, og, SU, zc);
    // 6. exclusive prefix over chunks
    prefix_kernel<<<BH, 256, 0, stream>>>(SU, zc);
    // 7. per-chunk outputs + mini-LN -> bf16
    phaseC_kernel<<<BH * NC, 256, 0, stream>>>(qkvb, og, SU, zc, mn_w, mn_b, attnb);
    // 8. out0 = attn @ Wproj + bproj  (bf16 MFMA, fp32 out)
    gemm_mfma_kernel<false><<<dim3(Dc / 128, BL / 128), 512, 0, stream>>>(
        attnb, WprojT, bproj, out0, BL, Dc, Dc);
}

// Round 4
// 116.341 us; speedup vs baseline: 2.5392x; 1.3893x over previous
//
#include <hip/hip_runtime.h>
#include <hip/hip_bf16.h>
#include <math.h>

// Problem constants
constexpr int Bc = 2, Lc = 1024, Dc = 768, Hc = 12, dh = 64, Rc = 128;
constexpr int BL = Bc * Lc;          // 2048 tokens
constexpr int TD = 3 * Dc;           // 2304
constexpr int CH = 64;               // chunk length
constexpr int NC = Lc / CH;          // 16 chunks per sequence
constexpr int BH = Bc * Hc;          // 24

typedef __attribute__((ext_vector_type(8))) short bf16x8;
typedef __attribute__((ext_vector_type(4))) float f32x4;

__device__ __forceinline__ float bf2f(short u) {
    union { float f; unsigned int i; } c;
    c.i = ((unsigned int)(unsigned short)u) << 16;
    return c.f;
}

#define GLOAD_LDS16(gp, lp)                                                        \
    __builtin_amdgcn_global_load_lds(                                              \
        (const __attribute__((address_space(1))) void*)(gp),                       \
        (__attribute__((address_space(3))) void*)(lp), 16, 0, 0)

// ---------------- LayerNorm over D=768, bf16 x_norm + bf16 raw-x copy ----------------
__global__ __launch_bounds__(256)
void ln_kernel(const float* __restrict__ x, const float* __restrict__ w,
               const float* __restrict__ bcoef, __hip_bfloat16* __restrict__ y,
               __hip_bfloat16* __restrict__ xb) {
    int row = blockIdx.x;
    const float* xr = x + (size_t)row * Dc;
    __hip_bfloat16* yr = y + (size_t)row * Dc;
    __hip_bfloat16* xbr = xb + (size_t)row * Dc;
    int tid = threadIdx.x;
    float v[3];
    float s = 0.f;
#pragma unroll
    for (int i = 0; i < 3; i++) { v[i] = xr[tid + i * 256]; s += v[i]; }
    __shared__ float red[256];
    red[tid] = s; __syncthreads();
    for (int off = 128; off > 0; off >>= 1) {
        if (tid < off) red[tid] += red[tid + off];
        __syncthreads();
    }
    float mu = red[0] / (float)Dc;
    __syncthreads();
    float s2 = 0.f;
#pragma unroll
    for (int i = 0; i < 3; i++) { float d = v[i] - mu; s2 += d * d; }
    red[tid] = s2; __syncthreads();
    for (int off = 128; off > 0; off >>= 1) {
        if (tid < off) red[tid] += red[tid + off];
        __syncthreads();
    }
    float rstd = rsqrtf(red[0] / (float)Dc + 1e-5f);
#pragma unroll
    for (int i = 0; i < 3; i++) {
        int c = tid + i * 256;
        yr[c] = __float2bfloat16((v[i] - mu) * rstd * w[c] + bcoef[c]);
        xbr[c] = __float2bfloat16(v[i]);
    }
}

// ---------------- Transpose + fp32->bf16: W[K][N] -> WT[N][K] ----------------
__global__ __launch_bounds__(256)
void transpose_bf16_kernel(const float* __restrict__ W, __hip_bfloat16* __restrict__ WT,
                           int K, int N) {
    __shared__ float t[32][33];
    int k0 = blockIdx.y * 32, n0 = blockIdx.x * 32;
    int tid = threadIdx.x;
    int r = tid >> 5, c = tid & 31;   // r in 0..7
#pragma unroll
    for (int i = 0; i < 4; i++)
        t[r + i * 8][c] = W[(size_t)(k0 + r + i * 8) * N + n0 + c];
    __syncthreads();
#pragma unroll
    for (int i = 0; i < 4; i++)
        WT[(size_t)(n0 + r + i * 8) * K + k0 + c] = __float2bfloat16(t[c][r + i * 8]);
}

// ---------------- bf16 MFMA GEMM, 2-phase global_load_lds pipeline ----------------
// C[M][N] = act(A[M][K] @ BT[N][K]^T + bias). 128x128 tile, BK=64, 512 thr = 8 waves.
// LDS: 2 buffers x (A 128x64 + B 128x64) bf16 = 64 KB. Linear rows (128 B) with
// XOR slot swizzle applied on BOTH the global source and the ds_read (rule #21).
// ACT: 0 none, 1 silu.
template <bool OUT_BF16, int ACT>
__global__ __launch_bounds__(512)
void gemm_mfma_kernel(const __hip_bfloat16* __restrict__ A,
                      const __hip_bfloat16* __restrict__ BT,
                      const float* __restrict__ bias,
                      void* __restrict__ Cout, int M, int N, int K) {
    __shared__ short lds[2][2][128 * 64];   // [buf][A/B][row*64 + elem]
    int tid = threadIdx.x;
    int wave = tid >> 6, lane = tid & 63;
    int l16 = lane & 15, l4 = lane >> 4;
    int m0 = blockIdx.y * 128, n0 = blockIdx.x * 128;

    // --- staging role: waves 0-3 stage A rows, waves 4-7 stage B rows ---
    int ab = wave >> 2;                       // 0 = A, 1 = B
    int r_in = lane >> 3;                     // 0..7 row within 8-row group
    int s_src = (lane & 7) ^ r_in;            // inverse-swizzled source slot
    const __hip_bfloat16* gbase = ab ? (BT + (size_t)n0 * K) : (A + (size_t)m0 * K);
    const __hip_bfloat16* gsrc =
        gbase + (size_t)((wave & 3) * 32 + r_in) * K + s_src * 8;

    // --- compute role: wave (wr, wc) owns 64x32 of C; frags 4(M) x 2(N) ---
    int wr = (wave >> 2) * 64, wc = (wave & 3) * 32;
    int xs = l16 & 7;                         // read-side XOR (== row & 7)

    f32x4 acc[4][2];
#pragma unroll
    for (int i = 0; i < 4; i++)
#pragma unroll
        for (int j = 0; j < 2; j++) acc[i][j] = f32x4{0.f, 0.f, 0.f, 0.f};

    auto stage = [&](int buf, int kt) {
        const __hip_bfloat16* g = gsrc + kt * 64;
        short* lb = &lds[buf][ab][(wave & 3) * 32 * 64];
#pragma unroll
        for (int i = 0; i < 4; i++)           // each instr: 8 rows x 1 KB
            GLOAD_LDS16(g + (size_t)i * 8 * K, lb + i * 8 * 64);
    };

    auto compute = [&](int buf) {
        const short* As = &lds[buf][0][0];
        const short* Bs = &lds[buf][1][0];
#pragma unroll
        for (int kk = 0; kk < 2; kk++) {
            bf16x8 af[4], bfr[2];
            int slot = (kk * 4 + l4) ^ xs;
#pragma unroll
            for (int f = 0; f < 4; f++)
                af[f] = *reinterpret_cast<const bf16x8*>(
                    &As[(wr + f * 16 + l16) * 64 + slot * 8]);
#pragma unroll
            for (int f = 0; f < 2; f++)
                bfr[f] = *reinterpret_cast<const bf16x8*>(
                    &Bs[(wc + f * 16 + l16) * 64 + slot * 8]);
#pragma unroll
            for (int i = 0; i < 4; i++)
#pragma unroll
                for (int j = 0; j < 2; j++)
                    acc[i][j] = __builtin_amdgcn_mfma_f32_16x16x32_bf16(
                        af[i], bfr[j], acc[i][j], 0, 0, 0);
        }
    };

    int NT = K / 64;
    int cur = 0;
    stage(0, 0);
    __syncthreads();                          // drains vmcnt(0): buf0 ready
    for (int t = 0; t < NT; t++) {
        if (t + 1 < NT) stage(cur ^ 1, t + 1);   // async, overlaps MFMA below
        compute(cur);
        if (t + 1 < NT) { __syncthreads(); cur ^= 1; }
    }

    int crow = l4 * 4;
#pragma unroll
    for (int i = 0; i < 4; i++) {
#pragma unroll
        for (int j = 0; j < 2; j++) {
            int col = n0 + wc + j * 16 + l16;
            float bb = bias ? bias[col] : 0.f;
#pragma unroll
            for (int r = 0; r < 4; r++) {
                int rowm = m0 + wr + i * 16 + crow + r;
                float v = acc[i][j][r] + bb;
                if (ACT == 1) v = v / (1.f + expf(-v));
                if (OUT_BF16)
                    ((__hip_bfloat16*)Cout)[(size_t)rowm * N + col] = __float2bfloat16(v);
                else
                    ((float*)Cout)[(size_t)rowm * N + col] = v;
            }
        }
    }
}

// ---------------- Gate params ----------------
__global__ __launch_bounds__(256)
void gate_kernel(const float* __restrict__ tbuf, const float* __restrict__ Wb2,
                 const float* __restrict__ temperature,
                 float* __restrict__ gate_out, float* __restrict__ og) {
    int id = blockIdx.x * 256 + threadIdx.x;   // < 24576
    int tok = id / Hc, h = id % Hc;
    const float* tr = tbuf + (size_t)tok * Rc;
    float p[5] = {};
    for (int r = 0; r < Rc; r++) {
        float tv = tr[r];
        const float* wr = Wb2 + r * (Hc * 5) + h * 5;
#pragma unroll
        for (int c = 0; c < 5; c++) p[c] = fmaf(tv, wr[c], p[c]);
    }
    const float PI = 3.14159265358979323846f;
    float sem_amp = 1.f / (1.f + expf(-p[0]));
    float sem_phase = tanhf(p[1]) * PI;
    float ctx_amp = 1.f / (1.f + expf(-p[2]));
    float ctx_phase = tanhf(p[3]) * PI;
    float temp = fminf(fmaxf(temperature[0], 0.1f), 2.0f);
    float inter = tanhf(sem_amp * ctx_amp * cosf(sem_phase - ctx_phase)) * temp;
    float g = 1.f / (1.f + expf(-inter));
    gate_out[id] = g;
    og[id] = 1.f + g;
}

// ---------------- Phase A: per-chunk U_c = K^T diag(1+g) V, zc = sum K ----------------
__global__ __launch_bounds__(256)
void phaseA_kernel(const __hip_bfloat16* __restrict__ qkv, const float* __restrict__ og,
                   float* __restrict__ SU, float* __restrict__ zc) {
    int bid = blockIdx.x;           // bh*16 + c
    int bh = bid >> 4, c = bid & 15;
    int b = bh / Hc, h = bh % Hc;
    int tok0 = b * Lc + c * CH;
    __shared__ float Ks[64 * 64];
    __shared__ float Vs[64 * 64];
    int tid = threadIdx.x;
#pragma unroll
    for (int i = 0; i < 2; i++) {
        int c8 = tid + i * 256;              // 16B chunk id, 0..511
        int tt = c8 >> 3, d8 = (c8 & 7) * 8;
        size_t rowoff = (size_t)(tok0 + tt) * TD + h * dh;
        bf16x8 k8 = *reinterpret_cast<const bf16x8*>(qkv + rowoff + Dc + d8);
        bf16x8 v8 = *reinterpret_cast<const bf16x8*>(qkv + rowoff + 2 * Dc + d8);
        float gv = og[(size_t)(tok0 + tt) * Hc + h];
        float kf[8], vf[8];
#pragma unroll
        for (int j = 0; j < 8; j++) {
            float kv = bf2f(k8[j]);
            kf[j] = kv > 0.f ? kv + 1.f : expf(kv);
            vf[j] = bf2f(v8[j]) * gv;
        }
        *reinterpret_cast<float4*>(&Ks[tt * 64 + d8])     = *reinterpret_cast<float4*>(&kf[0]);
        *reinterpret_cast<float4*>(&Ks[tt * 64 + d8 + 4]) = *reinterpret_cast<float4*>(&kf[4]);
        *reinterpret_cast<float4*>(&Vs[tt * 64 + d8])     = *reinterpret_cast<float4*>(&vf[0]);
        *reinterpret_cast<float4*>(&Vs[tt * 64 + d8 + 4]) = *reinterpret_cast<float4*>(&vf[4]);
    }
    __syncthreads();
    int e = tid & 63, d0 = (tid >> 6) * 16;
    float u[16] = {};
    for (int tt = 0; tt < 64; tt++) {
        float vv = Vs[tt * 64 + e];
#pragma unroll
        for (int j = 0; j < 16; j++)
            u[j] = fmaf(Ks[tt * 64 + d0 + j], vv, u[j]);
    }
    float* Uo = SU + (size_t)bid * 4096;
#pragma unroll
    for (int j = 0; j < 16; j++)
        Uo[(d0 + j) * 64 + e] = u[j];
    if (tid < 64) {
        float zsum = 0.f;
        for (int tt = 0; tt < 64; tt++) zsum += Ks[tt * 64 + tid];
        zc[bid * 64 + tid] = zsum;
    }
}

// ---------------- Phase B: exclusive prefix over chunks (one thread per element) ----------------
__global__ __launch_bounds__(256)
void prefix_kernel(float* __restrict__ SU, float* __restrict__ zc) {
    int gid = blockIdx.x * 256 + threadIdx.x;
    if (gid < BH * 4096) {
        int bh = gid >> 12, i = gid & 4095;
        float* S = SU + (size_t)bh * NC * 4096 + i;
        float r[NC];
#pragma unroll
        for (int cc = 0; cc < NC; cc++) r[cc] = S[cc * 4096];
        float run = 0.f;
#pragma unroll
        for (int cc = 0; cc < NC; cc++) { float tv = r[cc]; S[cc * 4096] = run; run += tv; }
    } else {
        int g2 = gid - BH * 4096;
        if (g2 < BH * 64) {
            int bh = g2 >> 6, i = g2 & 63;
            float* z = zc + (size_t)bh * NC * 64 + i;
            float r[NC];
#pragma unroll
            for (int cc = 0; cc < NC; cc++) r[cc] = z[cc * 64];
            float run = 0.f;
#pragma unroll
            for (int cc = 0; cc < NC; cc++) { float tv = r[cc]; z[cc * 64] = run; run += tv; }
        }
    }
}

// ---------------- Phase C: per-chunk output + mini-LN, bf16 out ----------------
__global__ __launch_bounds__(256)
void phaseC_kernel(const __hip_bfloat16* __restrict__ qkv, const float* __restrict__ og,
                   const float* __restrict__ SU, const float* __restrict__ zc,
                   const float* __restrict__ mn_w, const float* __restrict__ mn_b,
                   __hip_bfloat16* __restrict__ attn) {
    int bid = blockIdx.x;           // bh*16 + c
    int bh = bid >> 4, c = bid & 15;
    int b = bh / Hc, h = bh % Hc;
    int tok0 = b * Lc + c * CH;
    __shared__ float Qs[64 * 65];
    __shared__ float As[64 * 65];
    __shared__ float Ks[64 * 64];
    __shared__ float Vs[64 * 64];
    __shared__ float zs[64];
    __shared__ float dens[64];
    __shared__ float denp[4][64];
    int tid = threadIdx.x;
    int lane = tid & 63, grp = tid >> 6;
#pragma unroll
    for (int i = 0; i < 2; i++) {
        int c8 = tid + i * 256;
        int tt = c8 >> 3, d8 = (c8 & 7) * 8;
        size_t rowoff = (size_t)(tok0 + tt) * TD + h * dh;
        bf16x8 q8 = *reinterpret_cast<const bf16x8*>(qkv + rowoff + d8);
        bf16x8 k8 = *reinterpret_cast<const bf16x8*>(qkv + rowoff + Dc + d8);
        bf16x8 v8 = *reinterpret_cast<const bf16x8*>(qkv + rowoff + 2 * Dc + d8);
        float gv = og[(size_t)(tok0 + tt) * Hc + h];
        float kf[8], vf[8];
#pragma unroll
        for (int j = 0; j < 8; j++) {
            float qv = bf2f(q8[j]);
            Qs[tt * 65 + d8 + j] = qv > 0.f ? qv + 1.f : expf(qv);
            float kv = bf2f(k8[j]);
            kf[j] = kv > 0.f ? kv + 1.f : expf(kv);
            vf[j] = bf2f(v8[j]) * gv;
        }
        *reinterpret_cast<float4*>(&Ks[tt * 64 + d8])     = *reinterpret_cast<float4*>(&kf[0]);
        *reinterpret_cast<float4*>(&Ks[tt * 64 + d8 + 4]) = *reinterpret_cast<float4*>(&kf[4]);
        *reinterpret_cast<float4*>(&Vs[tt * 64 + d8])     = *reinterpret_cast<float4*>(&vf[0]);
        *reinterpret_cast<float4*>(&Vs[tt * 64 + d8 + 4]) = *reinterpret_cast<float4*>(&vf[4]);
    }
    if (tid < 64) zs[tid] = zc[bid * 64 + tid];
    __syncthreads();

    int t0 = grp * 16;
    float dotp[16] = {};
    for (int d = 0; d < 64; d++) {
        float ql = Qs[lane * 65 + d];
#pragma unroll
        for (int j = 0; j < 16; j++)
            dotp[j] = fmaf(ql, Ks[(t0 + j) * 64 + d], dotp[j]);
    }
    float dsum = 0.f;
#pragma unroll
    for (int j = 0; j < 16; j++) {
        float dv = (t0 + j) <= lane ? dotp[j] : 0.f;
        As[lane * 65 + t0 + j] = dv;
        dsum += dv;
    }
    denp[grp][lane] = dsum;
    __syncthreads();

    if (tid < 64) {
        int l = tid;
        float qz = 0.f;
        for (int d = 0; d < 64; d++) qz = fmaf(Qs[l * 65 + d], zs[d], qz);
        dens[l] = denp[0][l] + denp[1][l] + denp[2][l] + denp[3][l] + qz + 1e-6f;
    }
    __syncthreads();

    const float* Sg = SU + (size_t)bid * 4096;
    int e = lane, l0 = grp * 16;
    float acc[16] = {};
    for (int d = 0; d < 64; d++) {
        float sv = Sg[d * 64 + e];
#pragma unroll
        for (int i = 0; i < 16; i++)
            acc[i] = fmaf(Qs[(l0 + i) * 65 + d], sv, acc[i]);
    }
    for (int t = 0; t < 64; t++) {
        float vv = Vs[t * 64 + e];
#pragma unroll
        for (int i = 0; i < 16; i++)
            acc[i] = fmaf(As[(l0 + i) * 65 + t], vv, acc[i]);
    }
    float mnw = mn_w[e], mnb = mn_b[e];
#pragma unroll
    for (int i = 0; i < 16; i++) {
        int l = l0 + i;
        float val = acc[i] / dens[l];
        float s = val;
#pragma unroll
        for (int m = 1; m < 64; m <<= 1) s += __shfl_xor(s, m, 64);
        float mu = s * (1.f / 64.f);
        float dv = val - mu;
        float s2 = dv * dv;
#pragma unroll
        for (int m = 1; m < 64; m <<= 1) s2 += __shfl_xor(s2, m, 64);
        float rstd = rsqrtf(s2 * (1.f / 64.f) + 1e-5f);
        attn[(size_t)(tok0 + l) * Dc + h * dh + e] = __float2bfloat16(dv * rstd * mnw + mnb);
    }
}

extern "C" void kernel_launch(void* const* d_in, const int* in_sizes, int n_in,
                              void* d_out, int out_size, void* d_ws, size_t ws_size,
                              hipStream_t stream) {
    const float* x     = (const float*)d_in[0];
    const float* Wqkv  = (const float*)d_in[1];
    const float* bqkv  = (const float*)d_in[2];
    const float* Wb1   = (const float*)d_in[3];
    const float* Wb2   = (const float*)d_in[4];
    const float* temp  = (const float*)d_in[5];
    const float* Wproj = (const float*)d_in[6];
    const float* bproj = (const float*)d_in[7];
    const float* ln_w  = (const float*)d_in[8];
    const float* ln_b  = (const float*)d_in[9];
    const float* mn_w  = (const float*)d_in[10];
    const float* mn_b  = (const float*)d_in[11];

    float* out0 = (float*)d_out;                 // [2048, 768]
    float* gate = out0 + (size_t)BL * Dc;        // [2048, 12]

    float* ws   = (float*)d_ws;
    float* tbuf = ws;                            // 2048*128 f32
    float* og   = tbuf + (size_t)BL * Rc;        // 2048*12 f32
    float* SU   = og + (size_t)BL * Hc;          // 24*16*4096 f32
    float* zc   = SU + (size_t)BH * NC * 4096;   // 24*16*64 f32
    __hip_bfloat16* bfr = (__hip_bfloat16*)(zc + (size_t)BH * NC * 64);
    __hip_bfloat16* qkvb   = bfr;                        // 2048*2304 bf16
    __hip_bfloat16* xnb    = qkvb + (size_t)BL * TD;     // 2048*768 bf16
    __hip_bfloat16* xb     = xnb + (size_t)BL * Dc;      // 2048*768 bf16 (raw x)
    __hip_bfloat16* attnb  = xb + (size_t)BL * Dc;       // 2048*768 bf16
    __hip_bfloat16* WqkvT  = attnb + (size_t)BL * Dc;    // 2304*768 bf16
    __hip_bfloat16* WprojT = WqkvT + (size_t)TD * Dc;    // 768*768 bf16
    __hip_bfloat16* Wb1T   = WprojT + (size_t)Dc * Dc;   // 128*768 bf16

    // 0. weight transposes -> bf16 [N][K]
    transpose_bf16_kernel<<<dim3(TD / 32, Dc / 32), 256, 0, stream>>>(Wqkv, WqkvT, Dc, TD);
    transpose_bf16_kernel<<<dim3(Dc / 32, Dc / 32), 256, 0, stream>>>(Wproj, WprojT, Dc, Dc);
    transpose_bf16_kernel<<<dim3(Rc / 32, Dc / 32), 256, 0, stream>>>(Wb1, Wb1T, Dc, Rc);
    // 1. LayerNorm -> bf16 x_norm, bf16 raw x
    ln_kernel<<<BL, 256, 0, stream>>>(x, ln_w, ln_b, xnb, xb);
    // 2. qkv = x_norm @ Wqkv + bqkv   (bf16 MFMA, bf16 out)
    gemm_mfma_kernel<true, 0><<<dim3(TD / 128, BL / 128), 512, 0, stream>>>(
        xnb, WqkvT, bqkv, qkvb, BL, TD, Dc);
    // 3. t = silu(x @ Wb1)   (raw x, bf16 MFMA, fp32 out)
    gemm_mfma_kernel<false, 1><<<dim3(Rc / 128, BL / 128), 512, 0, stream>>>(
        xb, Wb1T, nullptr, tbuf, BL, Rc, Dc);
    // 4. gate + (1+gate)
    gate_kernel<<<BL * Hc / 256, 256, 0, stream>>>(tbuf, Wb2, temp, gate, og);
    // 5. per-chunk local KV state sums
    phaseA_kernel<<<BH * NC, 256, 0, stream>>>(qkvb, og, SU, zc);
    // 6. exclusive prefix over chunks
    prefix_kernel<<<(BH * 4096 + BH * 64 + 255) / 256, 256, 0, stream>>>(SU, zc);
    // 7. per-chunk outputs + mini-LN -> bf16
    phaseC_kernel<<<BH * NC, 256, 0, stream>>>(qkvb, og, SU, zc, mn_w, mn_b, attnb);
    // 8. out0 = attn @ Wproj + bproj  (bf16 MFMA, fp32 out)
    gemm_mfma_kernel<false, 0><<<dim3(Dc / 128, BL / 128), 512, 0, stream>>>(
        attnb, WprojT, bproj, out0, BL, Dc, Dc);
}